// Round 10
// baseline (144.118 us; speedup 1.0000x reference)
//
#include <hip/hip_runtime.h>
#include <math.h>

#define D 64
#define KNOTS 32
#define NSEG 31
#define G 208     // lookup cells per dim
#define TPAD 65   // tab2 row stride in u32: 65 ≡ 1 (mod 32) -> banks spread

typedef float f4v __attribute__((ext_vector_type(4)));
typedef _Float16 h2v __attribute__((ext_vector_type(2)));

__device__ __forceinline__ float softplus_f(float v) {
  // stable softplus, matches jax.nn.softplus in f32
  return fmaxf(v, 0.f) + log1pf(expf(-fabsf(v)));
}

// Fused PWL spline, single-LDS-hop tangent-table eval.
// tab2[c][d] = f16x2( A of segment at cell CENTER xc, y_true(xc) ).
// Eval: y = A*(x - xc) + yc. Centered form makes f16 quantization of A
// negligible (|x-xc| <= w/2). Error bound: sum|dA|*(w/2) per cell ~0.12
// << 0.186 threshold at G=208. Boundary cells c=0 / c=G-1 pinned to
// segments 0 / 30 so out-of-range extrapolation is exact.
__global__ __launch_bounds__(1024, 8) void pwl_fused(
    const float* __restrict__ x, const float* __restrict__ xk,
    const float* __restrict__ delta_raw, const float* __restrict__ scale_raw,
    const float* __restrict__ shift, float* __restrict__ out, int nrows) {
  __shared__ float kL[KNOTS * D];     // [j][d]   8192 B (build only)
  __shared__ float2 sAB[NSEG * D];    // [s][d]  15872 B (build only)
  __shared__ h2v tab2[G * TPAD];      // [c][d]  54080 B (stride 65 u32)
  __shared__ float invS[D], nloS[D], cwS[D], loS[D];  // 1024 B
  // total 79168 B -> 2 blocks/CU @ 1024 thr = 32 waves/CU

  const int tid = threadIdx.x;

  // ---- stage knots transposed: kL[j][d] ----
  for (int i = tid; i < D * KNOTS; i += blockDim.x) {
    int d = i >> 5, j = i & 31;
    kL[j * D + d] = xk[i];
  }
  __syncthreads();

  // ---- one thread per dim: exact per-segment A,B + grid params ----
  if (tid < D) {
    const int d = tid;
    float num = 0.f, den = 0.f;
    for (int s = 0; s < NSEG; ++s) {
      float sp = softplus_f(delta_raw[d * NSEG + s]) + 1e-4f;
      float dx = kL[(s + 1) * D + d] - kL[s * D + d];
      num += sp * dx;
      den += dx;
    }
    float avg = fmaxf(num / (den + 1e-8f), 1e-6f);
    float scale = softplus_f(scale_raw[d]) + 1e-3f;
    float sh = shift[d];
    float y = 0.f;
    for (int s = 0; s < NSEG; ++s) {
      float sp = softplus_f(delta_raw[d * NSEG + s]) + 1e-4f;
      float m = sp / avg;
      float k0 = kL[s * D + d];
      sAB[s * D + d] = make_float2(m * scale, (y - m * k0) * scale + sh);
      y += m * (kL[(s + 1) * D + d] - k0);
    }
    float lo = kL[1 * D + d];
    float hi = kL[(KNOTS - 1) * D + d];
    float inv = (float)G / (hi - lo);
    invS[d] = inv;
    nloS[d] = -lo * inv;
    cwS[d] = (hi - lo) / (float)G;
    loS[d] = lo;
  }
  __syncthreads();

  // ---- build tab2: segment at each cell center (binary search on kL) ----
  for (int p = tid; p < G * D; p += blockDim.x) {
    const int d = p & 63;
    const int c = p >> 6;
    const float xc = fmaf((float)c + 0.5f, cwS[d], loS[d]);
    int b = 0;
#pragma unroll
    for (int half = 16; half > 0; half >>= 1) {
      b += (kL[(b + half) * D + d] < xc) ? half : 0;  // count knots[1..31] < xc
    }
    int i0 = min(b, 30);
    if (c == 0) i0 = 0;          // exact left-tail extrapolation
    if (c == G - 1) i0 = 30;     // exact right-tail extrapolation
    float2 ab = sAB[i0 * D + d];
    float yc = fmaf(ab.x, xc, ab.y);
    h2v t;
    t.x = (_Float16)ab.x;
    t.y = (_Float16)yc;
    tab2[c * TPAD + d] = t;
  }
  __syncthreads();

  // ---- main loop: lane owns dims 4q..4q+3; 16 rows/group; 2-deep pipe ----
  const int lane = tid & 63;
  const int q = lane & 15;
  const int d0 = 4 * q;
  const float inv0 = invS[d0], nlo0 = nloS[d0], cw0 = cwS[d0], lo0 = loS[d0];
  const float inv1 = invS[d0 + 1], nlo1 = nloS[d0 + 1], cw1 = cwS[d0 + 1], lo1 = loS[d0 + 1];
  const float inv2 = invS[d0 + 2], nlo2 = nloS[d0 + 2], cw2 = cwS[d0 + 2], lo2 = loS[d0 + 2];
  const float inv3 = invS[d0 + 3], nlo3 = nloS[d0 + 3], cw3 = cwS[d0 + 3], lo3 = loS[d0 + 3];

  const f4v* __restrict__ x4 = (const f4v*)x;
  f4v* __restrict__ o4 = (f4v*)out;

  auto evalquad = [&](f4v xv) -> f4v {
    float cf0 = floorf(fminf(fmaxf(fmaf(xv.x, inv0, nlo0), 0.f), (float)(G - 1)));
    float cf1 = floorf(fminf(fmaxf(fmaf(xv.y, inv1, nlo1), 0.f), (float)(G - 1)));
    float cf2 = floorf(fminf(fmaxf(fmaf(xv.z, inv2, nlo2), 0.f), (float)(G - 1)));
    float cf3 = floorf(fminf(fmaxf(fmaf(xv.w, inv3, nlo3), 0.f), (float)(G - 1)));
    h2v t0 = tab2[(int)cf0 * TPAD + d0];
    h2v t1 = tab2[(int)cf1 * TPAD + d0 + 1];
    h2v t2 = tab2[(int)cf2 * TPAD + d0 + 2];
    h2v t3 = tab2[(int)cf3 * TPAD + d0 + 3];
    f4v r;
    r.x = fmaf((float)t0.x, xv.x - fmaf(cf0 + 0.5f, cw0, lo0), (float)t0.y);
    r.y = fmaf((float)t1.x, xv.y - fmaf(cf1 + 0.5f, cw1, lo1), (float)t1.y);
    r.z = fmaf((float)t2.x, xv.z - fmaf(cf2 + 0.5f, cw2, lo2), (float)t2.y);
    r.w = fmaf((float)t3.x, xv.w - fmaf(cf3 + 0.5f, cw3, lo3), (float)t3.y);
    return r;
  };

  const int gwave = (int)(blockIdx.x * blockDim.x + tid) >> 6;
  const int nwave = (int)(gridDim.x * blockDim.x) >> 6;
  const int ngroups = nrows >> 4;  // 16 rows per group (= 256 f4v per group)
  const int chunk = (ngroups + nwave - 1) / nwave;
  int g = gwave * chunk;
  const int gend = min(g + chunk, ngroups);

  f4v a0, a1, a2, a3;
  f4v b0, b1, b2, b3;

#define LOADG(p, gg)                                      \
  {                                                       \
    const int base_ = (gg) * 256 + lane;                  \
    p##0 = x4[base_];        p##1 = x4[base_ + 64];       \
    p##2 = x4[base_ + 128];  p##3 = x4[base_ + 192];      \
  }

#define PROCG(p, gg)                                                        \
  {                                                                         \
    const int base_ = (gg) * 256 + lane;                                    \
    f4v r_;                                                                 \
    r_ = evalquad(p##0); __builtin_nontemporal_store(r_, &o4[base_]);       \
    r_ = evalquad(p##1); __builtin_nontemporal_store(r_, &o4[base_ + 64]);  \
    r_ = evalquad(p##2); __builtin_nontemporal_store(r_, &o4[base_ + 128]); \
    r_ = evalquad(p##3); __builtin_nontemporal_store(r_, &o4[base_ + 192]); \
  }

  if (g < gend) {
    LOADG(a, g);
    while (true) {
      const int gn = g + 1;
      if (gn < gend) {
        LOADG(b, gn);
        PROCG(a, g);
        const int gnn = gn + 1;
        if (gnn < gend) {
          LOADG(a, gnn);
          PROCG(b, gn);
          g = gnn;
        } else {
          PROCG(b, gn);
          break;
        }
      } else {
        PROCG(a, g);
        break;
      }
    }
  }
#undef LOADG
#undef PROCG

  // ---- tail rows (nrows % 16): quarter-wave per row (unused at nrows=1e6) ----
  const int tr0 = ngroups << 4;
  for (int r = tr0 + gwave; r < nrows; r += nwave) {
    if (lane < 16) {
      const int bi = r * 16 + q;  // f4v index
      f4v xv = x4[bi];
      f4v rv = evalquad(xv);
      __builtin_nontemporal_store(rv, &o4[bi]);
    }
  }
}

extern "C" void kernel_launch(void* const* d_in, const int* in_sizes, int n_in,
                              void* d_out, int out_size, void* d_ws, size_t ws_size,
                              hipStream_t stream) {
  const float* x = (const float*)d_in[0];          // [N, D]
  const float* xk = (const float*)d_in[1];         // [D, K]
  const float* delta_raw = (const float*)d_in[2];  // [D, K-1]
  const float* scale_raw = (const float*)d_in[3];  // [D]
  const float* shift = (const float*)d_in[4];      // [D]
  float* out = (float*)d_out;

  const int nrows = in_sizes[0] / D;  // 1,000,000
  const int block = 1024;             // 16 waves; LDS 79.2 KB -> 2 blocks/CU
  const int grid = 512;               // exactly 2 per CU
  pwl_fused<<<grid, block, 0, stream>>>(x, xk, delta_raw, scale_raw, shift,
                                        out, nrows);
}

// Round 12
// 125.012 us; speedup vs baseline: 1.1528x; 1.1528x over previous
//
#include <hip/hip_runtime.h>
#include <math.h>

#define D 64
#define KNOTS 32
#define NSEG 31
#define G 512     // lookup cells per dim
#define TPAD 516  // tab row stride (u8)
#define SPAD 33   // sA/sB row stride (f32)

typedef float f4v __attribute__((ext_vector_type(4)));

__device__ __forceinline__ float softplus_f(float v) {
  return fmaxf(v, 0.f) + log1pf(expf(-fabsf(v)));
}

// Fused PWL spline (r8 numerics: u8 cell->segment table; exact for knot-free
// cells, error bounded ~0.09 << 0.186). Round-12: asm pipeline, FIXED order:
//   per step: [wait vmcnt(N) expcnt(0)] -> evalquad (regs) -> GLOAD next ->
//             STORE results.
// Queue is [L,S,L,S,...]: the awaited loads are always oldest -> waits never
// block on NT-store acks. r_ regs are live ACROSS the GLOAD asm so its
// outputs cannot alias pending-store data; expcnt(0) in the next wait closes
// the temp-reuse window. Peel waits 8/12/16, steady 20 (3 banks x 4 quads).
__global__ __launch_bounds__(512, 4) void pwl_fused(
    const float* __restrict__ x, const float* __restrict__ xk,
    const float* __restrict__ delta_raw, const float* __restrict__ scale_raw,
    const float* __restrict__ shift, float* __restrict__ out, int nrows) {
  __shared__ float kL[KNOTS * D];         // [j][sd]   8192 B (build only)
  __shared__ float sA[D * SPAD];          // [sd][s]   8448 B
  __shared__ float sB[D * SPAD];          // [sd][s]   8448 B
  __shared__ unsigned char tab[D * TPAD]; // [sd][c]  33024 B
  __shared__ float invS[D], nloS[D];      // [sd]       512 B (total 58624)

  const int tid = threadIdx.x;

  // ---- stage knots transposed + swizzled: d=4q+r -> sd=q+16r ----
  for (int i = tid; i < D * KNOTS; i += blockDim.x) {
    int d = i >> 5, j = i & 31;
    int sd = (d >> 2) | ((d & 3) << 4);
    kL[j * D + sd] = xk[i];
  }
  __syncthreads();

  // ---- one thread per (swizzled) dim: A/B tables + grid params ----
  if (tid < D) {
    const int sd = tid;
    const int d = ((sd & 15) << 2) | (sd >> 4);
    float num = 0.f, den = 0.f;
    for (int s = 0; s < NSEG; ++s) {
      float sp = softplus_f(delta_raw[d * NSEG + s]) + 1e-4f;
      float dx = kL[(s + 1) * D + sd] - kL[s * D + sd];
      num += sp * dx;
      den += dx;
    }
    float avg = fmaxf(num / (den + 1e-8f), 1e-6f);
    float scale = softplus_f(scale_raw[d]) + 1e-3f;
    float sh = shift[d];
    float y = 0.f;
    for (int s = 0; s < NSEG; ++s) {
      float sp = softplus_f(delta_raw[d * NSEG + s]) + 1e-4f;
      float m = sp / avg;
      float k0 = kL[s * D + sd];
      sA[sd * SPAD + s] = m * scale;
      sB[sd * SPAD + s] = (y - m * k0) * scale + sh;
      y += m * (kL[(s + 1) * D + sd] - k0);
    }
    float lo = kL[1 * D + sd];
    float hi = kL[(KNOTS - 1) * D + sd];
    float inv = (float)G / (hi - lo);
    invS[sd] = inv;
    nloS[sd] = -lo * inv;
  }
  __syncthreads();

  // ---- build tab via binary search (identical fma/clamp/trunc as eval) ----
  for (int p = tid; p < G * D; p += blockDim.x) {
    const int sd = p & 63;
    const int c = p >> 6;
    const float inv = invS[sd], nlo = nloS[sd];
    int b = 0;
#pragma unroll
    for (int half = 16; half > 0; half >>= 1) {
      float kv = kL[(b + half) * D + sd];
      float cf = fminf(fmaxf(fmaf(kv, inv, nlo), 0.f), (float)(G - 1));
      b += ((int)cf < c) ? half : 0;
    }
    tab[sd * TPAD + c] = (unsigned char)min(b, 30);
  }
  __syncthreads();

  // ---- main loop ----
  const int lane = tid & 63;
  const int q = lane & 15;
  const int sd0 = q, sd1 = q + 16, sd2 = q + 32, sd3 = q + 48;
  const float inv0 = invS[sd0], nlo0 = nloS[sd0];
  const float inv1 = invS[sd1], nlo1 = nloS[sd1];
  const float inv2 = invS[sd2], nlo2 = nloS[sd2];
  const float inv3 = invS[sd3], nlo3 = nloS[sd3];

  const float* xp = x;   // SGPR base for asm loads
  float* op = out;       // SGPR base for asm stores
  const f4v* __restrict__ x4 = (const f4v*)x;
  f4v* __restrict__ o4 = (f4v*)out;

  auto evalquad = [&](f4v xv) -> f4v {
    float cf0 = fminf(fmaxf(fmaf(xv.x, inv0, nlo0), 0.f), (float)(G - 1));
    float cf1 = fminf(fmaxf(fmaf(xv.y, inv1, nlo1), 0.f), (float)(G - 1));
    float cf2 = fminf(fmaxf(fmaf(xv.z, inv2, nlo2), 0.f), (float)(G - 1));
    float cf3 = fminf(fmaxf(fmaf(xv.w, inv3, nlo3), 0.f), (float)(G - 1));
    int i0 = tab[sd0 * TPAD + (int)cf0];
    int i1 = tab[sd1 * TPAD + (int)cf1];
    int i2 = tab[sd2 * TPAD + (int)cf2];
    int i3 = tab[sd3 * TPAD + (int)cf3];
    f4v r;
    r.x = fmaf(sA[sd0 * SPAD + i0], xv.x, sB[sd0 * SPAD + i0]);
    r.y = fmaf(sA[sd1 * SPAD + i1], xv.y, sB[sd1 * SPAD + i1]);
    r.z = fmaf(sA[sd2 * SPAD + i2], xv.z, sB[sd2 * SPAD + i2]);
    r.w = fmaf(sA[sd3 * SPAD + i3], xv.w, sB[sd3 * SPAD + i3]);
    return r;
  };

  const int wid = (int)(blockIdx.x * blockDim.x + tid) >> 6;
  const int nw = (int)(gridDim.x * blockDim.x) >> 6;
  const int ngroups = nrows >> 4;  // 16 rows/group = 256 f4v = 4096 B
  const int chunk = (ngroups + nw - 1) / nw;
  int g0 = wid * chunk;
  const int gend = min(g0 + chunk, ngroups);
  const int navail = (gend > g0) ? (gend - g0) : 0;
  const int nfull = (navail / 3) * 3;

  f4v A0, A1, A2, A3, B0, B1, B2, B3, C0, C1, C2, C3;

#define GLOADI(bk, voff)                                                 \
  asm volatile("global_load_dwordx4 %0, %4, %5 offset:0\n\t"             \
               "global_load_dwordx4 %1, %4, %5 offset:1024\n\t"          \
               "global_load_dwordx4 %2, %4, %5 offset:2048\n\t"          \
               "global_load_dwordx4 %3, %4, %5 offset:3072"              \
               : "=&v"(bk##0), "=&v"(bk##1), "=&v"(bk##2), "=&v"(bk##3)  \
               : "v"(voff), "s"(xp))

#define WAITP(NSTR)                                              \
  asm volatile("s_waitcnt vmcnt(" NSTR ") expcnt(0)" ::: "memory"); \
  __builtin_amdgcn_sched_barrier(0)

  // wait -> compute -> load-next -> store
#define STEP(bk, NSTR)                                                   \
  {                                                                      \
    WAITP(NSTR);                                                         \
    f4v r0_ = evalquad(bk##0);                                           \
    f4v r1_ = evalquad(bk##1);                                           \
    f4v r2_ = evalquad(bk##2);                                           \
    f4v r3_ = evalquad(bk##3);                                           \
    GLOADI(bk, voffN);                                                   \
    voffN = min(voffN + 4096u, maxL);                                    \
    asm volatile("global_store_dwordx4 %4, %0, %5 offset:0 nt\n\t"       \
                 "global_store_dwordx4 %4, %1, %5 offset:1024 nt\n\t"    \
                 "global_store_dwordx4 %4, %2, %5 offset:2048 nt\n\t"    \
                 "global_store_dwordx4 %4, %3, %5 offset:3072 nt"        \
                 :: "v"(r0_), "v"(r1_), "v"(r2_), "v"(r3_),              \
                    "v"(voffS), "s"(op));                                \
    voffS += 4096u;                                                      \
  }

  if (nfull >= 3) {
    const unsigned lb = (unsigned)lane * 16u;
    const unsigned maxL = (unsigned)(ngroups - 1) * 4096u + lb;
    unsigned voffS = (unsigned)g0 * 4096u + lb;
    unsigned voffN = voffS;
    GLOADI(A, voffN); voffN += 4096u;   // g0
    GLOADI(B, voffN); voffN += 4096u;   // g0+1
    GLOADI(C, voffN);                   // g0+2
    voffN = min(voffN + 4096u, maxL);

    // peel: waits 8 / 12 / 16, then steady 20 (queue: [L,S,L,S,L,S])
    STEP(A, "8");
    STEP(B, "12");
    STEP(C, "16");
    const int trips3 = nfull / 3 - 1;
    for (int t = 0; t < trips3; ++t) {
      STEP(A, "20");
      STEP(B, "20");
      STEP(C, "20");
    }
    asm volatile("s_waitcnt vmcnt(0)" ::: "memory");
    __builtin_amdgcn_sched_barrier(0);
    g0 += nfull;
  }
#undef GLOADI
#undef WAITP
#undef STEP

  // ---- remainder groups (<=2 per wave): normal compiler path ----
  for (int g = g0; g < gend; ++g) {
    const int base = g * 256 + lane;
    f4v v0 = x4[base];
    f4v v1 = x4[base + 64];
    f4v v2 = x4[base + 128];
    f4v v3 = x4[base + 192];
    f4v r0 = evalquad(v0);
    f4v r1 = evalquad(v1);
    f4v r2 = evalquad(v2);
    f4v r3 = evalquad(v3);
    __builtin_nontemporal_store(r0, &o4[base]);
    __builtin_nontemporal_store(r1, &o4[base + 64]);
    __builtin_nontemporal_store(r2, &o4[base + 128]);
    __builtin_nontemporal_store(r3, &o4[base + 192]);
  }

  // ---- tail rows (nrows % 16): quarter-wave per row (unused at 1e6) ----
  const int tr0 = ngroups << 4;
  for (int r = tr0 + wid; r < nrows; r += nw) {
    if (lane < 16) {
      const int bi = r * 16 + q;
      f4v xv = x4[bi];
      f4v rv = evalquad(xv);
      __builtin_nontemporal_store(rv, &o4[bi]);
    }
  }
}

extern "C" void kernel_launch(void* const* d_in, const int* in_sizes, int n_in,
                              void* d_out, int out_size, void* d_ws, size_t ws_size,
                              hipStream_t stream) {
  const float* x = (const float*)d_in[0];          // [N, D]
  const float* xk = (const float*)d_in[1];         // [D, K]
  const float* delta_raw = (const float*)d_in[2];  // [D, K-1]
  const float* scale_raw = (const float*)d_in[3];  // [D]
  const float* shift = (const float*)d_in[4];      // [D]
  float* out = (float*)d_out;

  const int nrows = in_sizes[0] / D;  // 1,000,000
  const int block = 512;              // 8 waves; LDS 58.6 KB -> 2 blocks/CU
  const int grid = 512;               // 2 per CU
  pwl_fused<<<grid, block, 0, stream>>>(x, xk, delta_raw, scale_raw, shift,
                                        out, nrows);
}